// Round 5
// baseline (722.756 us; speedup 1.0000x reference)
//
#include <hip/hip_runtime.h>

// Problem constants: B=32, T=512, C=22, FREQ=192, HID=128
#define CC 22
#define FF 192
#define HH 128
#define NBT (32 * 512)

typedef __attribute__((ext_vector_type(8))) __bf16 bf16x8;
typedef __attribute__((ext_vector_type(8))) short s16x8;
typedef __attribute__((ext_vector_type(4))) float f32x4;

__device__ __forceinline__ float bf2f(unsigned short u) {
    union { unsigned int i; float f; } v;
    v.i = ((unsigned int)u) << 16;
    return v.f;
}

// round-to-nearest-even f32 -> bf16 (scalar; cold paths only)
__device__ __forceinline__ unsigned short f2bf(float f) {
    union { float f; unsigned int i; } v;
    v.f = f;
    return (unsigned short)((v.i + 0x7fffu + ((v.i >> 16) & 1u)) >> 16);
}

__device__ __forceinline__ void split2(float v, unsigned short& h, unsigned short& l) {
    h = f2bf(v);
    float r = v - bf2f(h);
    l = f2bf(r);
}

// HW packed convert: dst.lo16 = bf16(a), dst.hi16 = bf16(b)  (RNE)
__device__ __forceinline__ unsigned int cvt_pk_bf16(float a, float b) {
    unsigned int r;
    asm("v_cvt_pk_bf16_f32 %0, %1, %2" : "=v"(r) : "v"(a), "v"(b));
    return r;
}

// split a PAIR of f32 into packed-hi and packed-lo bf16 dwords (6 VALU ops)
__device__ __forceinline__ void split_pk2(float a, float b,
                                          unsigned int& hi, unsigned int& lo) {
    hi = cvt_pk_bf16(a, b);
    union { unsigned int i; float f; } ha, hb;
    ha.i = hi << 16;
    hb.i = hi & 0xffff0000u;
    lo = cvt_pk_bf16(a - ha.f, b - hb.f);
}

// load 8 consecutive fp32 from global, split into hi/lo bf16x8 fragments
__device__ __forceinline__ void load_split8(const float* __restrict__ p,
                                            bf16x8& fh, bf16x8& fl) {
    const float4 a = *(const float4*)p;
    const float4 b = *(const float4*)(p + 4);
    uint4 h, l;
    split_pk2(a.x, a.y, h.x, l.x);
    split_pk2(a.z, a.w, h.y, l.y);
    split_pk2(b.x, b.y, h.z, l.z);
    split_pk2(b.z, b.w, h.w, l.w);
    fh = __builtin_bit_cast(bf16x8, h);
    fl = __builtin_bit_cast(bf16x8, l);
}

__device__ __forceinline__ bf16x8 bzero8() {
    s16x8 z = {0, 0, 0, 0, 0, 0, 0, 0};
    return __builtin_bit_cast(bf16x8, z);
}

// y-slab addressing: [128][32] bf16 (64B rows), 2-bit XOR swizzle within row.
__device__ __forceinline__ int ybyte(int row, int b) {
    return row * 64 + (b ^ (((row >> 1) & 3) << 4));
}

// Self-detect: inputs bf16 (1) or fp32 (0). A is uniform[0,1]; if bf16, every
// ushort read as bf16 lies in [0,1.0001]. Wave-uniform verdict via __all.
// (fp32 A: mantissa-low ushorts decode to random bf16 -> fails w.p. 1-0.25^32.)
__device__ __forceinline__ int inputs_are_bf16(const unsigned short* __restrict__ A,
                                               int tid) {
    const float v = bf2f(A[tid & 63]);
    return __all(v >= 0.0f && v <= 1.0001f);
}

// ---------------------------------------------------------------------------
// fp32 inputs, split-precision (hi+lo bf16, 3 MFMA combos), zero-staging path.
//
//   stage : A only -> hi/lo [32][40] LDS (barrier)
//   P1: D1[c][h]  = x·W0^T   (x,W0 fragments DIRECT from global fp32,
//                             split in-register)      -> yT[h][c] swizzled slab
//   P2: D2[c'][h] = A·y + b0, relu                    -> h2T[h][c'] SAME slab
//   P3: D3[h][c'] = h2T·A^T (swapped)  -> barrier -> h3[c'][h] (aliases A+y)
//   P4: D4[o][c'] = W1·h3^T + b1 (W1 direct fp32), relu -> reduce, mean, out
//
// Barriers: stage-A, pre-h3-store (all waves done reading A/y regions),
// post-h3-store. LDS total 21504B.
// ---------------------------------------------------------------------------
__device__ void run_block_split(
    const float* __restrict__ xg, const float* __restrict__ Ag,
    const float* __restrict__ W0g, const float* __restrict__ b0g,
    const float* __restrict__ W1g, const float* __restrict__ b1g,
    float* __restrict__ outg, int bt, int tid, char* smem)
{
    unsigned short* sAh  = (unsigned short*)smem;              // [32][40] 2560B
    unsigned short* sAl  = (unsigned short*)(smem + 2560);     // [32][40] 2560B
    char*           syh  = smem + 5120;                        // [128][32] 8192B (y then h2)
    char*           syl  = smem + 13312;                       // [128][32] 8192B
    unsigned short* sh3h = (unsigned short*)smem;              // [32][136] 8704B (aliases A+y)
    unsigned short* sh3l = (unsigned short*)(smem + 8704);     // [32][136] 8704B

    // ---- stage A [22][22] fp32 -> hi/lo [32][40] zero-padded ----
    {
        const float* Ap = Ag + (size_t)bt * (CC * CC);
        for (int idx = tid; idx < 32 * 40; idx += 256) {
            const int r = idx / 40;
            const int c = idx - r * 40;
            unsigned short h = 0, l = 0;
            if (r < CC && c < CC) split2(Ap[r * CC + c], h, l);
            sAh[idx] = h;
            sAl[idx] = l;
        }
    }
    __syncthreads();

    const int lane = tid & 63;
    const int wid  = tid >> 6;
    const int lr   = lane & 15;   // fragment row/col within 16
    const int lk   = lane >> 4;   // k-group (8 elems each)
    const int hb   = wid * 32;    // this wave's h-column block

    const f32x4 vzero = {0.f, 0.f, 0.f, 0.f};

    // A-operand fragments (held in regs through P2/P3; A LDS region is
    // clobbered by h3 only after the pre-store barrier)
    bf16x8 Afh[2], Afl[2];
    #pragma unroll
    for (int t = 0; t < 2; ++t) {
        const int off = (t * 16 + lr) * 40 + lk * 8;
        Afh[t] = *(const bf16x8*)(sAh + off);
        Afl[t] = *(const bf16x8*)(sAl + off);
    }

    // ---- P1: D1[c][h] = x @ W0^T (3-combo); x/W0 direct from global ----
    {
        const float* xb = xg + (size_t)bt * (CC * FF);
        f32x4 acc[2][2];
        #pragma unroll
        for (int mt = 0; mt < 2; ++mt)
            #pragma unroll
            for (int nt = 0; nt < 2; ++nt) acc[mt][nt] = vzero;

        #pragma unroll
        for (int ks = 0; ks < 6; ++ks) {
            bf16x8 xfh[2], xfl[2];
            #pragma unroll
            for (int mt = 0; mt < 2; ++mt) {
                const int row = mt * 16 + lr;
                const int rr  = (row < CC) ? row : 0;   // clamp (zeroed below)
                bf16x8 fh, fl;
                load_split8(xb + rr * FF + ks * 32 + lk * 8, fh, fl);
                if (row >= CC) { fh = bzero8(); fl = bzero8(); }
                xfh[mt] = fh; xfl[mt] = fl;
            }
            bf16x8 wfh[2], wfl[2];
            #pragma unroll
            for (int nt = 0; nt < 2; ++nt) {
                const int hcol = hb + nt * 16 + lr;
                load_split8(W0g + hcol * FF + ks * 32 + lk * 8, wfh[nt], wfl[nt]);
            }
            #pragma unroll
            for (int mt = 0; mt < 2; ++mt)
                #pragma unroll
                for (int nt = 0; nt < 2; ++nt) {
                    acc[mt][nt] = __builtin_amdgcn_mfma_f32_16x16x32_bf16(xfh[mt], wfh[nt], acc[mt][nt], 0, 0, 0);
                    acc[mt][nt] = __builtin_amdgcn_mfma_f32_16x16x32_bf16(xfl[mt], wfh[nt], acc[mt][nt], 0, 0, 0);
                    acc[mt][nt] = __builtin_amdgcn_mfma_f32_16x16x32_bf16(xfh[mt], wfl[nt], acc[mt][nt], 0, 0, 0);
                }
        }
        #pragma unroll
        for (int mt = 0; mt < 2; ++mt)
            #pragma unroll
            for (int nt = 0; nt < 2; ++nt) {
                const int hcol = hb + nt * 16 + lr;
                uint2 hv, lv;
                split_pk2(acc[mt][nt][0], acc[mt][nt][1], hv.x, lv.x);
                split_pk2(acc[mt][nt][2], acc[mt][nt][3], hv.y, lv.y);
                const int boff = ybyte(hcol, mt * 32 + lk * 8);
                *(uint2*)(syh + boff) = hv;
                *(uint2*)(syl + boff) = lv;
            }
    }

    // ---- P2: D2[c'][h] = A @ y + b0, relu; h2T into SAME slab (intra-wave) ----
    {
        f32x4 acc[2][2];
        #pragma unroll
        for (int nt = 0; nt < 2; ++nt) {
            const float b = b0g[hb + nt * 16 + lr];
            const f32x4 bv = {b, b, b, b};
            acc[0][nt] = bv;
            acc[1][nt] = bv;
        }
        bf16x8 yfh[2], yfl[2];
        #pragma unroll
        for (int nt = 0; nt < 2; ++nt) {
            const int boff = ybyte(hb + nt * 16 + lr, lk * 16);
            yfh[nt] = *(const bf16x8*)(syh + boff);
            yfl[nt] = *(const bf16x8*)(syl + boff);
        }
        asm volatile("" ::: "memory");  // keep y reads before h2 writes
        #pragma unroll
        for (int mt = 0; mt < 2; ++mt)
            #pragma unroll
            for (int nt = 0; nt < 2; ++nt) {
                acc[mt][nt] = __builtin_amdgcn_mfma_f32_16x16x32_bf16(Afh[mt], yfh[nt], acc[mt][nt], 0, 0, 0);
                acc[mt][nt] = __builtin_amdgcn_mfma_f32_16x16x32_bf16(Afl[mt], yfh[nt], acc[mt][nt], 0, 0, 0);
                acc[mt][nt] = __builtin_amdgcn_mfma_f32_16x16x32_bf16(Afh[mt], yfl[nt], acc[mt][nt], 0, 0, 0);
            }
        #pragma unroll
        for (int mt = 0; mt < 2; ++mt)
            #pragma unroll
            for (int nt = 0; nt < 2; ++nt) {
                const int hcol = hb + nt * 16 + lr;
                uint2 hv, lv;
                split_pk2(fmaxf(acc[mt][nt][0], 0.f), fmaxf(acc[mt][nt][1], 0.f), hv.x, lv.x);
                split_pk2(fmaxf(acc[mt][nt][2], 0.f), fmaxf(acc[mt][nt][3], 0.f), hv.y, lv.y);
                const int boff = ybyte(hcol, mt * 32 + lk * 8);
                *(uint2*)(syh + boff) = hv;
                *(uint2*)(syl + boff) = lv;
            }
    }

    // ---- P3 (swapped): D3[h][c'] = h2T @ A^T -> h3[c'][h] (aliases A+y) ----
    {
        f32x4 acc[2][2];
        #pragma unroll
        for (int mt = 0; mt < 2; ++mt)
            #pragma unroll
            for (int ct = 0; ct < 2; ++ct) acc[mt][ct] = vzero;

        bf16x8 gfh[2], gfl[2];   // h2T rows h (own slab), k=c contiguous
        #pragma unroll
        for (int mt = 0; mt < 2; ++mt) {
            const int boff = ybyte(hb + mt * 16 + lr, lk * 16);
            gfh[mt] = *(const bf16x8*)(syh + boff);
            gfl[mt] = *(const bf16x8*)(syl + boff);
        }
        #pragma unroll
        for (int mt = 0; mt < 2; ++mt)
            #pragma unroll
            for (int ct = 0; ct < 2; ++ct) {
                acc[mt][ct] = __builtin_amdgcn_mfma_f32_16x16x32_bf16(gfh[mt], Afh[ct], acc[mt][ct], 0, 0, 0);
                acc[mt][ct] = __builtin_amdgcn_mfma_f32_16x16x32_bf16(gfl[mt], Afh[ct], acc[mt][ct], 0, 0, 0);
                acc[mt][ct] = __builtin_amdgcn_mfma_f32_16x16x32_bf16(gfh[mt], Afl[ct], acc[mt][ct], 0, 0, 0);
            }
        __syncthreads();   // all waves done reading A/y regions (h3 clobbers them)
        // D rows = h = hb + mt*16 + lk*4 + r, cols = c' = ct*16 + lr
        #pragma unroll
        for (int mt = 0; mt < 2; ++mt)
            #pragma unroll
            for (int ct = 0; ct < 2; ++ct) {
                const int cp = ct * 16 + lr;
                uint2 hv, lv;
                split_pk2(acc[mt][ct][0], acc[mt][ct][1], hv.x, lv.x);
                split_pk2(acc[mt][ct][2], acc[mt][ct][3], hv.y, lv.y);
                const int e = cp * 136 + hb + mt * 16 + lk * 4;
                *(uint2*)&sh3h[e] = hv;
                *(uint2*)&sh3l[e] = lv;
            }
    }
    __syncthreads();   // h3 is read cross-wave in P4

    // ---- P4: D4[o][c'] = W1 @ h3^T + b1 (W1 direct fp32), relu; mean c'<22 ----
    {
        f32x4 acc[2][2];
        #pragma unroll
        for (int mt = 0; mt < 2; ++mt) {
            const float4 bv = *(const float4*)(b1g + hb + mt * 16 + lk * 4);
            const f32x4 bb = {bv.x, bv.y, bv.z, bv.w};
            acc[mt][0] = bb;
            acc[mt][1] = bb;
        }
        #pragma unroll
        for (int ks = 0; ks < 4; ++ks) {
            bf16x8 wfh[2], wfl[2], hfh[2], hfl[2];
            #pragma unroll
            for (int mt = 0; mt < 2; ++mt) {
                const int o = hb + mt * 16 + lr;
                load_split8(W1g + o * HH + ks * 32 + lk * 8, wfh[mt], wfl[mt]);
            }
            #pragma unroll
            for (int ct = 0; ct < 2; ++ct) {
                const int off = (ct * 16 + lr) * 136 + ks * 32 + lk * 8;
                hfh[ct] = *(const bf16x8*)(sh3h + off);
                hfl[ct] = *(const bf16x8*)(sh3l + off);
            }
            #pragma unroll
            for (int mt = 0; mt < 2; ++mt)
                #pragma unroll
                for (int ct = 0; ct < 2; ++ct) {
                    acc[mt][ct] = __builtin_amdgcn_mfma_f32_16x16x32_bf16(wfh[mt], hfh[ct], acc[mt][ct], 0, 0, 0);
                    acc[mt][ct] = __builtin_amdgcn_mfma_f32_16x16x32_bf16(wfl[mt], hfh[ct], acc[mt][ct], 0, 0, 0);
                    acc[mt][ct] = __builtin_amdgcn_mfma_f32_16x16x32_bf16(wfh[mt], hfl[ct], acc[mt][ct], 0, 0, 0);
                }
        }
        float s[2][4];
        #pragma unroll
        for (int mt = 0; mt < 2; ++mt)
            #pragma unroll
            for (int r = 0; r < 4; ++r) {
                float v = fmaxf(acc[mt][0][r], 0.f);              // c' = lr
                if (lr < CC - 16) v += fmaxf(acc[mt][1][r], 0.f); // c' = 16+lr
                s[mt][r] = v;
            }
        #pragma unroll
        for (int m = 1; m < 16; m <<= 1)
            #pragma unroll
            for (int mt = 0; mt < 2; ++mt)
                #pragma unroll
                for (int r = 0; r < 4; ++r)
                    s[mt][r] += __shfl_xor(s[mt][r], m);

        if (lr == 0) {
            const float inv = 1.0f / 22.0f;
            #pragma unroll
            for (int mt = 0; mt < 2; ++mt) {
                float4 o4;
                o4.x = s[mt][0] * inv;
                o4.y = s[mt][1] * inv;
                o4.z = s[mt][2] * inv;
                o4.w = s[mt][3] * inv;
                *(float4*)(outg + (size_t)bt * HH + hb + mt * 16 + lk * 4) = o4;
            }
        }
    }
}

// ---------------------------------------------------------------------------
// bf16-input path (contingency): identical structure, single-precision frags,
// x/W fragments direct from global bf16. LDS: A[32][40] 2560 + y 8192 = 10752;
// h3 [32][136] (8704B) aliases A+y.
// ---------------------------------------------------------------------------
__device__ void run_block_bf16(
    const unsigned short* __restrict__ xg, const unsigned short* __restrict__ Ag,
    const unsigned short* __restrict__ W0g, const unsigned short* __restrict__ b0g,
    const unsigned short* __restrict__ W1g, const unsigned short* __restrict__ b1g,
    unsigned short* __restrict__ outg, int bt, int tid, char* smem)
{
    unsigned short* sAm = (unsigned short*)smem;           // [32][40] 2560B
    char*           sy  = smem + 2560;                     // [128][32] 8192B swizzled
    unsigned short* sh3 = (unsigned short*)smem;           // [32][136] 8704B aliases

    // stage A zero-padded
    {
        const unsigned short* Ap = Ag + (size_t)bt * (CC * CC);
        for (int idx = tid; idx < 32 * 40; idx += 256) {
            const int r = idx / 40;
            const int c = idx - r * 40;
            sAm[idx] = (r < CC && c < CC) ? Ap[r * CC + c] : (unsigned short)0;
        }
    }
    __syncthreads();

    const int lane = tid & 63;
    const int wid  = tid >> 6;
    const int lr   = lane & 15;
    const int lk   = lane >> 4;
    const int hb   = wid * 32;
    const f32x4 vzero = {0.f, 0.f, 0.f, 0.f};

    bf16x8 Af[2];
    #pragma unroll
    for (int t = 0; t < 2; ++t)
        Af[t] = *(const bf16x8*)(sAm + (t * 16 + lr) * 40 + lk * 8);

    // P1: y = x @ W0^T
    {
        const unsigned short* xb = xg + (size_t)bt * (CC * FF);
        f32x4 acc[2][2];
        #pragma unroll
        for (int mt = 0; mt < 2; ++mt)
            #pragma unroll
            for (int nt = 0; nt < 2; ++nt) acc[mt][nt] = vzero;
        #pragma unroll
        for (int ks = 0; ks < 6; ++ks) {
            bf16x8 xf[2], wf[2];
            #pragma unroll
            for (int mt = 0; mt < 2; ++mt) {
                const int row = mt * 16 + lr;
                const int rr  = (row < CC) ? row : 0;
                bf16x8 f = *(const bf16x8*)(xb + rr * FF + ks * 32 + lk * 8);
                if (row >= CC) f = bzero8();
                xf[mt] = f;
            }
            #pragma unroll
            for (int nt = 0; nt < 2; ++nt)
                wf[nt] = *(const bf16x8*)(W0g + ((size_t)(hb + nt * 16 + lr)) * FF + ks * 32 + lk * 8);
            #pragma unroll
            for (int mt = 0; mt < 2; ++mt)
                #pragma unroll
                for (int nt = 0; nt < 2; ++nt)
                    acc[mt][nt] = __builtin_amdgcn_mfma_f32_16x16x32_bf16(xf[mt], wf[nt], acc[mt][nt], 0, 0, 0);
        }
        #pragma unroll
        for (int mt = 0; mt < 2; ++mt)
            #pragma unroll
            for (int nt = 0; nt < 2; ++nt) {
                const int hcol = hb + nt * 16 + lr;
                uint2 hv;
                hv.x = cvt_pk_bf16(acc[mt][nt][0], acc[mt][nt][1]);
                hv.y = cvt_pk_bf16(acc[mt][nt][2], acc[mt][nt][3]);
                *(uint2*)(sy + ybyte(hcol, mt * 32 + lk * 8)) = hv;
            }
    }

    // P2: h2 = relu(A @ y + b0) into same slab
    {
        f32x4 acc[2][2];
        #pragma unroll
        for (int nt = 0; nt < 2; ++nt) {
            const float b = bf2f(b0g[hb + nt * 16 + lr]);
            const f32x4 bv = {b, b, b, b};
            acc[0][nt] = bv;
            acc[1][nt] = bv;
        }
        bf16x8 yf[2];
        #pragma unroll
        for (int nt = 0; nt < 2; ++nt)
            yf[nt] = *(const bf16x8*)(sy + ybyte(hb + nt * 16 + lr, lk * 16));
        asm volatile("" ::: "memory");
        #pragma unroll
        for (int mt = 0; mt < 2; ++mt)
            #pragma unroll
            for (int nt = 0; nt < 2; ++nt)
                acc[mt][nt] = __builtin_amdgcn_mfma_f32_16x16x32_bf16(Af[mt], yf[nt], acc[mt][nt], 0, 0, 0);
        #pragma unroll
        for (int mt = 0; mt < 2; ++mt)
            #pragma unroll
            for (int nt = 0; nt < 2; ++nt) {
                const int hcol = hb + nt * 16 + lr;
                uint2 hv;
                hv.x = cvt_pk_bf16(fmaxf(acc[mt][nt][0], 0.f), fmaxf(acc[mt][nt][1], 0.f));
                hv.y = cvt_pk_bf16(fmaxf(acc[mt][nt][2], 0.f), fmaxf(acc[mt][nt][3], 0.f));
                *(uint2*)(sy + ybyte(hcol, mt * 32 + lk * 8)) = hv;
            }
    }

    // P3: h3 = h2T @ A^T (swapped); store h3[c'][h]
    {
        f32x4 acc[2][2];
        #pragma unroll
        for (int mt = 0; mt < 2; ++mt)
            #pragma unroll
            for (int ct = 0; ct < 2; ++ct) acc[mt][ct] = vzero;
        bf16x8 gf[2];
        #pragma unroll
        for (int mt = 0; mt < 2; ++mt)
            gf[mt] = *(const bf16x8*)(sy + ybyte(hb + mt * 16 + lr, lk * 16));
        #pragma unroll
        for (int mt = 0; mt < 2; ++mt)
            #pragma unroll
            for (int ct = 0; ct < 2; ++ct)
                acc[mt][ct] = __builtin_amdgcn_mfma_f32_16x16x32_bf16(gf[mt], Af[ct], acc[mt][ct], 0, 0, 0);
        __syncthreads();
        #pragma unroll
        for (int mt = 0; mt < 2; ++mt)
            #pragma unroll
            for (int ct = 0; ct < 2; ++ct) {
                const int cp = ct * 16 + lr;
                uint2 hv;
                hv.x = cvt_pk_bf16(acc[mt][ct][0], acc[mt][ct][1]);
                hv.y = cvt_pk_bf16(acc[mt][ct][2], acc[mt][ct][3]);
                *(uint2*)&sh3[cp * 136 + hb + mt * 16 + lk * 4] = hv;
            }
    }
    __syncthreads();

    // P4: out = mean_c relu(W1 @ h3^T + b1)
    {
        f32x4 acc[2][2];
        #pragma unroll
        for (int mt = 0; mt < 2; ++mt) {
            const ushort4 bu = *(const ushort4*)(b1g + hb + mt * 16 + lk * 4);
            f32x4 bvv = {bf2f(bu.x), bf2f(bu.y), bf2f(bu.z), bf2f(bu.w)};
            acc[mt][0] = bvv;
            acc[mt][1] = bvv;
        }
        #pragma unroll
        for (int ks = 0; ks < 4; ++ks) {
            bf16x8 wf[2], hf[2];
            #pragma unroll
            for (int mt = 0; mt < 2; ++mt)
                wf[mt] = *(const bf16x8*)(W1g + ((size_t)(hb + mt * 16 + lr)) * HH + ks * 32 + lk * 8);
            #pragma unroll
            for (int ct = 0; ct < 2; ++ct)
                hf[ct] = *(const bf16x8*)(sh3 + (ct * 16 + lr) * 136 + ks * 32 + lk * 8);
            #pragma unroll
            for (int mt = 0; mt < 2; ++mt)
                #pragma unroll
                for (int ct = 0; ct < 2; ++ct)
                    acc[mt][ct] = __builtin_amdgcn_mfma_f32_16x16x32_bf16(wf[mt], hf[ct], acc[mt][ct], 0, 0, 0);
        }
        float s[2][4];
        #pragma unroll
        for (int mt = 0; mt < 2; ++mt)
            #pragma unroll
            for (int r = 0; r < 4; ++r) {
                float v = fmaxf(acc[mt][0][r], 0.f);
                if (lr < CC - 16) v += fmaxf(acc[mt][1][r], 0.f);
                s[mt][r] = v;
            }
        #pragma unroll
        for (int m = 1; m < 16; m <<= 1)
            #pragma unroll
            for (int mt = 0; mt < 2; ++mt)
                #pragma unroll
                for (int r = 0; r < 4; ++r)
                    s[mt][r] += __shfl_xor(s[mt][r], m);
        if (lr == 0) {
            const float inv = 1.0f / 22.0f;
            #pragma unroll
            for (int mt = 0; mt < 2; ++mt) {
                uint2 st;
                st.x = cvt_pk_bf16(s[mt][0] * inv, s[mt][1] * inv);
                st.y = cvt_pk_bf16(s[mt][2] * inv, s[mt][3] * inv);
                *(uint2*)(outg + (size_t)bt * HH + hb + mt * 16 + lk * 4) = st;
            }
        }
    }
}

__global__ __launch_bounds__(256) void tgcn_kernel(
    const void* __restrict__ x, const void* __restrict__ A,
    const void* __restrict__ W0, const void* __restrict__ b0,
    const void* __restrict__ W1, const void* __restrict__ b1,
    void* __restrict__ out)
{
    __shared__ __align__(16) char smem[21504];

    const int tid = threadIdx.x;
    const int bt  = blockIdx.x;
    const int isbf = inputs_are_bf16((const unsigned short*)A, tid);

    if (isbf) {
        run_block_bf16((const unsigned short*)x, (const unsigned short*)A,
                       (const unsigned short*)W0, (const unsigned short*)b0,
                       (const unsigned short*)W1, (const unsigned short*)b1,
                       (unsigned short*)out, bt, tid, smem);
    } else {
        run_block_split((const float*)x, (const float*)A,
                        (const float*)W0, (const float*)b0,
                        (const float*)W1, (const float*)b1,
                        (float*)out, bt, tid, smem);
    }
}

extern "C" void kernel_launch(void* const* d_in, const int* in_sizes, int n_in,
                              void* d_out, int out_size, void* d_ws, size_t ws_size,
                              hipStream_t stream) {
    tgcn_kernel<<<NBT, 256, 0, stream>>>(
        d_in[0], d_in[1], d_in[2], d_in[3], d_in[4], d_in[5], d_out);
}

// Round 6
// 708.086 us; speedup vs baseline: 1.0207x; 1.0207x over previous
//
#include <hip/hip_runtime.h>

// Problem constants: B=32, T=512, C=22, FREQ=192, HID=128
#define CC 22
#define FF 192
#define HH 128
#define NBT (32 * 512)
#define NBLK 2048
#define NITER (NBT / NBLK)   // 8

typedef __attribute__((ext_vector_type(8))) __bf16 bf16x8;
typedef __attribute__((ext_vector_type(8))) short s16x8;
typedef __attribute__((ext_vector_type(4))) float f32x4;

__device__ __forceinline__ float bf2f(unsigned short u) {
    union { unsigned int i; float f; } v;
    v.i = ((unsigned int)u) << 16;
    return v.f;
}

// round-to-nearest-even f32 -> bf16 (scalar; cold paths only)
__device__ __forceinline__ unsigned short f2bf(float f) {
    union { float f; unsigned int i; } v;
    v.f = f;
    return (unsigned short)((v.i + 0x7fffu + ((v.i >> 16) & 1u)) >> 16);
}

__device__ __forceinline__ void split2(float v, unsigned short& h, unsigned short& l) {
    h = f2bf(v);
    float r = v - bf2f(h);
    l = f2bf(r);
}

// HW packed convert: dst.lo16 = bf16(a), dst.hi16 = bf16(b)  (RNE)
__device__ __forceinline__ unsigned int cvt_pk_bf16(float a, float b) {
    unsigned int r;
    asm("v_cvt_pk_bf16_f32 %0, %1, %2" : "=v"(r) : "v"(a), "v"(b));
    return r;
}

// split a PAIR of f32 into packed-hi and packed-lo bf16 dwords (6 VALU ops)
__device__ __forceinline__ void split_pk2(float a, float b,
                                          unsigned int& hi, unsigned int& lo) {
    hi = cvt_pk_bf16(a, b);
    union { unsigned int i; float f; } ha, hb;
    ha.i = hi << 16;
    hb.i = hi & 0xffff0000u;
    lo = cvt_pk_bf16(a - ha.f, b - hb.f);
}

__device__ __forceinline__ bf16x8 bzero8() {
    s16x8 z = {0, 0, 0, 0, 0, 0, 0, 0};
    return __builtin_bit_cast(bf16x8, z);
}

// y-slab addressing: [128][32] bf16 (64B rows), 2-bit XOR swizzle within row.
__device__ __forceinline__ int ybyte(int row, int b) {
    return row * 64 + (b ^ (((row >> 1) & 3) << 4));
}

// Self-detect: inputs bf16 (1) or fp32 (0). A is uniform[0,1]; if bf16, every
// ushort read as bf16 lies in [0,1.0001]. Wave-uniform verdict via __all.
__device__ __forceinline__ int inputs_are_bf16(const unsigned short* __restrict__ A,
                                               int tid) {
    const float v = bf2f(A[tid & 63]);
    return __all(v >= 0.0f && v <= 1.0001f);
}

// ws layout (ushort indices, base = d_ws):
//   W0h [0,24576) W0l [24576,49152) W1h [49152,65536) W1l [65536,81920)
#define WS0H 0
#define WS0L 24576
#define WS1H 49152
#define WS1L 65536

__global__ void convert_weights(const float* __restrict__ W0g,
                                const float* __restrict__ W1g,
                                const unsigned short* __restrict__ Aany,
                                unsigned short* __restrict__ wsW) {
    if (inputs_are_bf16(Aany, threadIdx.x)) return;  // bf16 inputs: skip
    const int i = blockIdx.x * 256 + threadIdx.x;
    if (i < HH * FF) {
        unsigned short h, l;
        split2(W0g[i], h, l);
        wsW[WS0H + i] = h;
        wsW[WS0L + i] = l;
    } else {
        const int j = i - HH * FF;
        if (j < HH * HH) {
            unsigned short h, l;
            split2(W1g[j], h, l);
            wsW[WS1H + j] = h;
            wsW[WS1L + j] = l;
        }
    }
}

// ---------------------------------------------------------------------------
// fp32 VALU fallback (only if workspace too small). Per-iteration body.
// ---------------------------------------------------------------------------
__device__ void run_block_f32(
    const float* __restrict__ xg, const float* __restrict__ Ag,
    const float* __restrict__ W0g, const float* __restrict__ b0g,
    const float* __restrict__ W1g, const float* __restrict__ b1g,
    float* __restrict__ outg, int bt, int tid,
    float* sA, float* sX, float* sH1)
{
    float* sH2  = sX;
    float* sH3  = sH1;
    float* sRed = sA;

    const float* Ap = Ag + (size_t)bt * (CC * CC);
    for (int i = tid; i < CC * CC; i += 256) sA[i] = Ap[i];
    const float4* xp = (const float4*)(xg + (size_t)bt * (CC * FF));
    for (int i = tid; i < CC * FF / 4; i += 256) ((float4*)sX)[i] = xp[i];
    __syncthreads();

    for (int idx4 = tid; idx4 < CC * FF / 4; idx4 += 256) {
        const int c  = idx4 / (FF / 4);
        const int fq = idx4 - c * (FF / 4);
        float4 acc = make_float4(0.f, 0.f, 0.f, 0.f);
        #pragma unroll
        for (int j = 0; j < CC; ++j) {
            const float  a  = sA[c * CC + j];
            const float4 xv = *(const float4*)&sX[j * FF + 4 * fq];
            acc.x += a * xv.x; acc.y += a * xv.y;
            acc.z += a * xv.z; acc.w += a * xv.w;
        }
        ((float4*)sH1)[idx4] = acc;
    }
    __syncthreads();

    const int h  = tid & 127;
    const int ty = tid >> 7;

    {
        float acc[11];
        const float bb = b0g[h];
        #pragma unroll
        for (int i = 0; i < 11; ++i) acc[i] = bb;
        #pragma unroll 4
        for (int fq = 0; fq < FF / 4; ++fq) {
            float4 u = ((const float4*)(W0g + h * FF))[fq];
            #pragma unroll
            for (int i = 0; i < 11; ++i) {
                const float4 xv = *(const float4*)&sH1[(2 * i + ty) * FF + 4 * fq];
                acc[i] = fmaf(xv.x, u.x, fmaf(xv.y, u.y, fmaf(xv.z, u.z, fmaf(xv.w, u.w, acc[i]))));
            }
        }
        #pragma unroll
        for (int i = 0; i < 11; ++i)
            sH2[(2 * i + ty) * HH + h] = fmaxf(acc[i], 0.f);
    }
    __syncthreads();

    for (int idx4 = tid; idx4 < CC * HH / 4; idx4 += 256) {
        const int c  = idx4 / (HH / 4);
        const int kq = idx4 - c * (HH / 4);
        float4 acc = make_float4(0.f, 0.f, 0.f, 0.f);
        #pragma unroll
        for (int j = 0; j < CC; ++j) {
            const float  a  = sA[c * CC + j];
            const float4 xv = *(const float4*)&sH2[j * HH + 4 * kq];
            acc.x += a * xv.x; acc.y += a * xv.y;
            acc.z += a * xv.z; acc.w += a * xv.w;
        }
        ((float4*)sH3)[idx4] = acc;
    }
    __syncthreads();

    {
        float acc[11];
        const float bb = b1g[h];
        #pragma unroll
        for (int i = 0; i < 11; ++i) acc[i] = bb;
        #pragma unroll 4
        for (int kq = 0; kq < HH / 4; ++kq) {
            float4 u = ((const float4*)(W1g + h * HH))[kq];
            #pragma unroll
            for (int i = 0; i < 11; ++i) {
                const float4 xv = *(const float4*)&sH3[(2 * i + ty) * HH + 4 * kq];
                acc[i] = fmaf(xv.x, u.x, fmaf(xv.y, u.y, fmaf(xv.z, u.z, fmaf(xv.w, u.w, acc[i]))));
            }
        }
        float s = 0.f;
        #pragma unroll
        for (int i = 0; i < 11; ++i) s += fmaxf(acc[i], 0.f);
        sRed[ty * HH + h] = s;
    }
    __syncthreads();

    if (ty == 0) {
        const float m = (sRed[h] + sRed[HH + h]) * (1.0f / 22.0f);
        outg[(size_t)bt * HH + h] = m;
    }
}

// ---------------------------------------------------------------------------
// fp32 split-precision path: persistent block, NITER bt-tiles, cross-iteration
// register prefetch of x/A (stage writes from regs; next loads issued right
// after the stage barrier and fly under P1..P4 compute).
//
// LDS (39104B, 4 blocks/CU):
//   sxh [22][200] 0..8800, sxl 8800..17600, sAh [32][40] 17600..20160,
//   sAl 20160..22720, syh 22720..30912, syl 30912..39104.
//   h3 [32][136] hi/lo aliases ONLY the x region (0..17408).
// Barriers/iter: B1 post-stage, B2 post-P1 (x reads done), B3 post-h3-store,
// B4 end-of-iter (h3 reads done before next stage overwrites).
// ---------------------------------------------------------------------------
__device__ void run_split_loop(
    const float* __restrict__ xg, const float* __restrict__ Ag,
    const float* __restrict__ b0g, const float* __restrict__ b1g,
    const unsigned short* __restrict__ wsW,
    float* __restrict__ outg, int blk, int tid, char* smem)
{
    unsigned short* sxh  = (unsigned short*)smem;
    unsigned short* sxl  = (unsigned short*)(smem + 8800);
    unsigned short* sAh  = (unsigned short*)(smem + 17600);
    unsigned short* sAl  = (unsigned short*)(smem + 20160);
    char*           syh  = smem + 22720;
    char*           syl  = smem + 30912;
    unsigned short* sh3h = (unsigned short*)smem;
    unsigned short* sh3l = (unsigned short*)(smem + 8704);

    const unsigned short* W0h = wsW + WS0H;
    const unsigned short* W0l = wsW + WS0L;
    const unsigned short* W1h = wsW + WS1H;
    const unsigned short* W1l = wsW + WS1L;

    // zero the A pad cells ONCE (disjoint from valid cells -> no race with stage)
    for (int idx = tid; idx < 32 * 40; idx += 256) {
        const int r = idx / 40;
        const int c = idx - r * 40;
        if (!(r < CC && c < CC)) { sAh[idx] = 0; sAl[idx] = 0; }
    }

    const int lane = tid & 63;
    const int wid  = tid >> 6;
    const int lr   = lane & 15;
    const int lk   = lane >> 4;
    const int hb   = wid * 32;

    const f32x4 vzero = {0.f, 0.f, 0.f, 0.f};

    // ---- prefetch registers for iteration 0 ----
    float4 xr0, xr1, xr2, xr3, xr4v;
    float  a0v, a1v = 0.f;
    {
        const float4* xp4 = (const float4*)xg + (size_t)blk * (CC * FF / 4);
        xr0 = xp4[tid];
        xr1 = xp4[tid + 256];
        xr2 = xp4[tid + 512];
        xr3 = xp4[tid + 768];
        if (tid < 32) xr4v = xp4[tid + 1024];
        const float* Ap = Ag + (size_t)blk * (CC * CC);
        a0v = Ap[tid];
        if (tid < CC * CC - 256) a1v = Ap[tid + 256];
    }

    for (int it = 0; it < NITER; ++it) {
        const int bt = it * NBLK + blk;

        // ---- stage x/A from regs (split via cvt_pk) ----
        {
            float4 xv[4] = {xr0, xr1, xr2, xr3};
            #pragma unroll
            for (int k = 0; k < 4; ++k) {
                const int idx4 = tid + 256 * k;
                const int c = idx4 / (FF / 4);
                const int q = idx4 - c * (FF / 4);
                uint2 hv, lv;
                split_pk2(xv[k].x, xv[k].y, hv.x, lv.x);
                split_pk2(xv[k].z, xv[k].w, hv.y, lv.y);
                *(uint2*)&sxh[c * 200 + 4 * q] = hv;
                *(uint2*)&sxl[c * 200 + 4 * q] = lv;
            }
            if (tid < 32) {
                const int idx4 = tid + 1024;
                const int c = idx4 / (FF / 4);
                const int q = idx4 - c * (FF / 4);
                uint2 hv, lv;
                split_pk2(xr4v.x, xr4v.y, hv.x, lv.x);
                split_pk2(xr4v.z, xr4v.w, hv.y, lv.y);
                *(uint2*)&sxh[c * 200 + 4 * q] = hv;
                *(uint2*)&sxl[c * 200 + 4 * q] = lv;
            }
            {
                const int r = tid / CC, c = tid - r * CC;
                unsigned short h, l;
                split2(a0v, h, l);
                sAh[r * 40 + c] = h;
                sAl[r * 40 + c] = l;
                if (tid < CC * CC - 256) {
                    const int i2 = tid + 256;
                    const int r2 = i2 / CC, c2 = i2 - r2 * CC;
                    split2(a1v, h, l);
                    sAh[r2 * 40 + c2] = h;
                    sAl[r2 * 40 + c2] = l;
                }
            }
        }
        __syncthreads();   // B1

        // ---- issue global loads for next iteration (fly under compute) ----
        if (it + 1 < NITER) {
            const int btn = (it + 1) * NBLK + blk;
            const float4* xp4 = (const float4*)xg + (size_t)btn * (CC * FF / 4);
            xr0 = xp4[tid];
            xr1 = xp4[tid + 256];
            xr2 = xp4[tid + 512];
            xr3 = xp4[tid + 768];
            if (tid < 32) xr4v = xp4[tid + 1024];
            const float* Ap = Ag + (size_t)btn * (CC * CC);
            a0v = Ap[tid];
            if (tid < CC * CC - 256) a1v = Ap[tid + 256];
        }

        // A-operand fragments (A region is never clobbered within the iter)
        bf16x8 Afh[2], Afl[2];
        #pragma unroll
        for (int t = 0; t < 2; ++t) {
            const int off = (t * 16 + lr) * 40 + lk * 8;
            Afh[t] = *(const bf16x8*)(sAh + off);
            Afl[t] = *(const bf16x8*)(sAl + off);
        }

        // ---- P1: D1[c][h] = x @ W0^T (3-combo); yT[h][c] into own slab ----
        {
            f32x4 acc[2][2];
            #pragma unroll
            for (int mt = 0; mt < 2; ++mt)
                #pragma unroll
                for (int nt = 0; nt < 2; ++nt) acc[mt][nt] = vzero;

            #pragma unroll
            for (int ks = 0; ks < 6; ++ks) {
                bf16x8 xfh[2], xfl[2];
                #pragma unroll
                for (int mt = 0; mt < 2; ++mt) {
                    const int row = mt * 16 + lr;
                    const int rr  = (row < CC) ? row : 0;
                    const int off = rr * 200 + ks * 32 + lk * 8;
                    bf16x8 fh = *(const bf16x8*)(sxh + off);
                    bf16x8 fl = *(const bf16x8*)(sxl + off);
                    if (row >= CC) { fh = bzero8(); fl = bzero8(); }
                    xfh[mt] = fh; xfl[mt] = fl;
                }
                bf16x8 wfh[2], wfl[2];
                #pragma unroll
                for (int nt = 0; nt < 2; ++nt) {
                    const int hcol = hb + nt * 16 + lr;
                    const int off  = hcol * FF + ks * 32 + lk * 8;
                    wfh[nt] = *(const bf16x8*)(W0h + off);
                    wfl[nt] = *(const bf16x8*)(W0l + off);
                }
                #pragma unroll
                for (int mt = 0; mt < 2; ++mt)
                    #pragma unroll
                    for (int nt = 0; nt < 2; ++nt) {
                        acc[mt][nt] = __builtin_amdgcn_mfma_f32_16x16x32_bf16(xfh[mt], wfh[nt], acc[mt][nt], 0, 0, 0);
                        acc[mt][nt] = __builtin_amdgcn_mfma_f32_16x16x32_bf16(xfl[mt], wfh[nt], acc[mt][nt], 0, 0, 0);
                        acc[mt][nt] = __builtin_amdgcn_mfma_f32_16x16x32_bf16(xfh[mt], wfl[nt], acc[mt][nt], 0, 0, 0);
                    }
            }
            #pragma unroll
            for (int mt = 0; mt < 2; ++mt)
                #pragma unroll
                for (int nt = 0; nt < 2; ++nt) {
                    const int hcol = hb + nt * 16 + lr;
                    uint2 hv, lv;
                    split_pk2(acc[mt][nt][0], acc[mt][nt][1], hv.x, lv.x);
                    split_pk2(acc[mt][nt][2], acc[mt][nt][3], hv.y, lv.y);
                    const int boff = ybyte(hcol, mt * 32 + lk * 8);
                    *(uint2*)(syh + boff) = hv;
                    *(uint2*)(syl + boff) = lv;
                }
        }
        __syncthreads();   // B2: all waves done reading x (h3 will clobber it)

        // ---- P2: D2[c'][h] = A @ y + b0, relu; h2T into SAME slab ----
        {
            f32x4 acc[2][2];
            #pragma unroll
            for (int nt = 0; nt < 2; ++nt) {
                const float b = b0g[hb + nt * 16 + lr];
                const f32x4 bv = {b, b, b, b};
                acc[0][nt] = bv;
                acc[1][nt] = bv;
            }
            bf16x8 yfh[2], yfl[2];
            #pragma unroll
            for (int nt = 0; nt < 2; ++nt) {
                const int boff = ybyte(hb + nt * 16 + lr, lk * 16);
                yfh[nt] = *(const bf16x8*)(syh + boff);
                yfl[nt] = *(const bf16x8*)(syl + boff);
            }
            asm volatile("" ::: "memory");  // keep y reads before h2 writes
            #pragma unroll
            for (int mt = 0; mt < 2; ++mt)
                #pragma unroll
                for (int nt = 0; nt < 2; ++nt) {
                    acc[mt][nt] = __builtin_amdgcn_mfma_f32_16x16x32_bf16(Afh[mt], yfh[nt], acc[mt][nt], 0, 0, 0);
                    acc[mt][nt] = __builtin_amdgcn_mfma_f32_16x16x32_bf16(Afl[mt], yfh[nt], acc[mt][nt], 0, 0, 0);
                    acc[mt][nt] = __builtin_amdgcn_mfma_f32_16x16x32_bf16(Afh[mt], yfl[nt], acc[mt][nt], 0, 0, 0);
                }
            #pragma unroll
            for (int mt = 0; mt < 2; ++mt)
                #pragma unroll
                for (int nt = 0; nt < 2; ++nt) {
                    const int hcol = hb + nt * 16 + lr;
                    uint2 hv, lv;
                    split_pk2(fmaxf(acc[mt][nt][0], 0.f), fmaxf(acc[mt][nt][1], 0.f), hv.x, lv.x);
                    split_pk2(fmaxf(acc[mt][nt][2], 0.f), fmaxf(acc[mt][nt][3], 0.f), hv.y, lv.y);
                    const int boff = ybyte(hcol, mt * 32 + lk * 8);
                    *(uint2*)(syh + boff) = hv;
                    *(uint2*)(syl + boff) = lv;
                }
        }

        // ---- P3 (swapped): D3[h][c'] = h2T @ A^T -> h3[c'][h] ----
        {
            f32x4 acc[2][2];
            #pragma unroll
            for (int mt = 0; mt < 2; ++mt)
                #pragma unroll
                for (int ct = 0; ct < 2; ++ct) acc[mt][ct] = vzero;

            bf16x8 gfh[2], gfl[2];
            #pragma unroll
            for (int mt = 0; mt < 2; ++mt) {
                const int boff = ybyte(hb + mt * 16 + lr, lk * 16);
                gfh[mt] = *(const bf16x8*)(syh + boff);
                gfl[mt] = *(const bf16x8*)(syl + boff);
            }
            #pragma unroll
            for (int mt = 0; mt < 2; ++mt)
                #pragma unroll
                for (int ct = 0; ct < 2; ++ct) {
                    acc[mt][ct] = __builtin_amdgcn_mfma_f32_16x16x32_bf16(gfh[mt], Afh[ct], acc[mt][ct], 0, 0, 0);
                    acc[mt][ct] = __builtin_amdgcn_mfma_f32_16x16x32_bf16(gfl[mt], Afh[ct], acc[mt][ct], 0, 0, 0);
                    acc[mt][ct] = __builtin_amdgcn_mfma_f32_16x16x32_bf16(gfh[mt], Afl[ct], acc[mt][ct], 0, 0, 0);
                }
            #pragma unroll
            for (int mt = 0; mt < 2; ++mt)
                #pragma unroll
                for (int ct = 0; ct < 2; ++ct) {
                    const int cp = ct * 16 + lr;
                    uint2 hv, lv;
                    split_pk2(acc[mt][ct][0], acc[mt][ct][1], hv.x, lv.x);
                    split_pk2(acc[mt][ct][2], acc[mt][ct][3], hv.y, lv.y);
                    const int e = cp * 136 + hb + mt * 16 + lk * 4;
                    *(uint2*)&sh3h[e] = hv;
                    *(uint2*)&sh3l[e] = lv;
                }
        }
        __syncthreads();   // B3: h3 complete, read cross-wave in P4

        // ---- P4: D4[o][c'] = W1 @ h3^T + b1, relu; mean over c'<22 ----
        {
            f32x4 acc[2][2];
            #pragma unroll
            for (int mt = 0; mt < 2; ++mt) {
                const float4 bv = *(const float4*)(b1g + hb + mt * 16 + lk * 4);
                const f32x4 bb = {bv.x, bv.y, bv.z, bv.w};
                acc[mt][0] = bb;
                acc[mt][1] = bb;
            }
            #pragma unroll
            for (int ks = 0; ks < 4; ++ks) {
                bf16x8 wfh[2], wfl[2], hfh[2], hfl[2];
                #pragma unroll
                for (int mt = 0; mt < 2; ++mt) {
                    const int o   = hb + mt * 16 + lr;
                    const int off = o * HH + ks * 32 + lk * 8;
                    wfh[mt] = *(const bf16x8*)(W1h + off);
                    wfl[mt] = *(const bf16x8*)(W1l + off);
                }
                #pragma unroll
                for (int ct = 0; ct < 2; ++ct) {
                    const int off = (ct * 16 + lr) * 136 + ks * 32 + lk * 8;
                    hfh[ct] = *(const bf16x8*)(sh3h + off);
                    hfl[ct] = *(const bf16x8*)(sh3l + off);
                }
                #pragma unroll
                for (int mt = 0; mt < 2; ++mt)
                    #pragma unroll
                    for (int ct = 0; ct < 2; ++ct) {
                        acc[mt][ct] = __builtin_amdgcn_mfma_f32_16x16x32_bf16(wfh[mt], hfh[ct], acc[mt][ct], 0, 0, 0);
                        acc[mt][ct] = __builtin_amdgcn_mfma_f32_16x16x32_bf16(wfl[mt], hfh[ct], acc[mt][ct], 0, 0, 0);
                        acc[mt][ct] = __builtin_amdgcn_mfma_f32_16x16x32_bf16(wfh[mt], hfl[ct], acc[mt][ct], 0, 0, 0);
                    }
            }
            float s[2][4];
            #pragma unroll
            for (int mt = 0; mt < 2; ++mt)
                #pragma unroll
                for (int r = 0; r < 4; ++r) {
                    float v = fmaxf(acc[mt][0][r], 0.f);
                    if (lr < CC - 16) v += fmaxf(acc[mt][1][r], 0.f);
                    s[mt][r] = v;
                }
            #pragma unroll
            for (int m = 1; m < 16; m <<= 1)
                #pragma unroll
                for (int mt = 0; mt < 2; ++mt)
                    #pragma unroll
                    for (int r = 0; r < 4; ++r)
                        s[mt][r] += __shfl_xor(s[mt][r], m);

            if (lr == 0) {
                const float inv = 1.0f / 22.0f;
                #pragma unroll
                for (int mt = 0; mt < 2; ++mt) {
                    float4 o4;
                    o4.x = s[mt][0] * inv;
                    o4.y = s[mt][1] * inv;
                    o4.z = s[mt][2] * inv;
                    o4.w = s[mt][3] * inv;
                    *(float4*)(outg + (size_t)bt * HH + hb + mt * 16 + lk * 4) = o4;
                }
            }
        }
        __syncthreads();   // B4: h3/x + A regions free for next stage
    }
}

// ---------------------------------------------------------------------------
// bf16-input path (contingency), per-iteration body (r5 structure).
// LDS: sAm [32][40] 0..2560, sy 2560..10752; sh3 [32][136] aliases 0..8704.
// ---------------------------------------------------------------------------
__device__ void run_block_bf16(
    const unsigned short* __restrict__ xg, const unsigned short* __restrict__ Ag,
    const unsigned short* __restrict__ W0g, const unsigned short* __restrict__ b0g,
    const unsigned short* __restrict__ W1g, const unsigned short* __restrict__ b1g,
    unsigned short* __restrict__ outg, int bt, int tid, char* smem)
{
    unsigned short* sAm = (unsigned short*)smem;
    char*           sy  = smem + 2560;
    unsigned short* sh3 = (unsigned short*)smem;

    {
        const unsigned short* Ap = Ag + (size_t)bt * (CC * CC);
        for (int idx = tid; idx < 32 * 40; idx += 256) {
            const int r = idx / 40;
            const int c = idx - r * 40;
            sAm[idx] = (r < CC && c < CC) ? Ap[r * CC + c] : (unsigned short)0;
        }
    }
    __syncthreads();

    const int lane = tid & 63;
    const int wid  = tid >> 6;
    const int lr   = lane & 15;
    const int lk   = lane >> 4;
    const int hb   = wid * 32;
    const f32x4 vzero = {0.f, 0.f, 0.f, 0.f};

    bf16x8 Af[2];
    #pragma unroll
    for (int t = 0; t < 2; ++t)
        Af[t] = *(const bf16x8*)(sAm + (t * 16 + lr) * 40 + lk * 8);

    {
        const unsigned short* xb = xg + (size_t)bt * (CC * FF);
        f32x4 acc[2][2];
        #pragma unroll
        for (int mt = 0; mt < 2; ++mt)
            #pragma unroll
            for (int nt = 0; nt < 2; ++nt) acc[mt][nt] = vzero;
        #pragma unroll
        for (int ks = 0; ks < 6; ++ks) {
            bf16x8 xf[2], wf[2];
            #pragma unroll
            for (int mt = 0; mt < 2; ++mt) {
                const int row = mt * 16 + lr;
                const int rr  = (row < CC) ? row : 0;
                bf16x8 f = *(const bf16x8*)(xb + rr * FF + ks * 32 + lk * 8);
                if (row >= CC) f = bzero8();
                xf[mt] = f;
            }
            #pragma unroll
            for (int nt = 0; nt < 2; ++nt)
                wf[nt] = *(const bf16x8*)(W0g + ((size_t)(hb + nt * 16 + lr)) * FF + ks * 32 + lk * 8);
            #pragma unroll
            for (int mt = 0; mt < 2; ++mt)
                #pragma unroll
                for (int nt = 0; nt < 2; ++nt)
                    acc[mt][nt] = __builtin_amdgcn_mfma_f32_16x16x32_bf16(xf[mt], wf[nt], acc[mt][nt], 0, 0, 0);
        }
        #pragma unroll
        for (int mt = 0; mt < 2; ++mt)
            #pragma unroll
            for (int nt = 0; nt < 2; ++nt) {
                const int hcol = hb + nt * 16 + lr;
                uint2 hv;
                hv.x = cvt_pk_bf16(acc[mt][nt][0], acc[mt][nt][1]);
                hv.y = cvt_pk_bf16(acc[mt][nt][2], acc[mt][nt][3]);
                *(uint2*)(sy + ybyte(hcol, mt * 32 + lk * 8)) = hv;
            }
    }

    {
        f32x4 acc[2][2];
        #pragma unroll
        for (int nt = 0; nt < 2; ++nt) {
            const float b = bf2f(b0g[hb + nt * 16 + lr]);
            const f32x4 bv = {b, b, b, b};
            acc[0][nt] = bv;
            acc[1][nt] = bv;
        }
        bf16x8 yf[2];
        #pragma unroll
        for (int nt = 0; nt < 2; ++nt)
            yf[nt] = *(const bf16x8*)(sy + ybyte(hb + nt * 16 + lr, lk * 16));
        asm volatile("" ::: "memory");
        #pragma unroll
        for (int mt = 0; mt < 2; ++mt)
            #pragma unroll
            for (int nt = 0; nt < 2; ++nt)
                acc[mt][nt] = __builtin_amdgcn_mfma_f32_16x16x32_bf16(Af[mt], yf[nt], acc[mt][nt], 0, 0, 0);
        #pragma unroll
        for (int mt = 0; mt < 2; ++mt)
            #pragma unroll
            for (int nt = 0; nt < 2; ++nt) {
                const int hcol = hb + nt * 16 + lr;
                uint2 hv;
                hv.x = cvt_pk_bf16(fmaxf(acc[mt][nt][0], 0.f), fmaxf(acc[mt][nt][1], 0.f));
                hv.y = cvt_pk_bf16(fmaxf(acc[mt][nt][2], 0.f), fmaxf(acc[mt][nt][3], 0.f));
                *(uint2*)(sy + ybyte(hcol, mt * 32 + lk * 8)) = hv;
            }
    }

    {
        f32x4 acc[2][2];
        #pragma unroll
        for (int mt = 0; mt < 2; ++mt)
            #pragma unroll
            for (int ct = 0; ct < 2; ++ct) acc[mt][ct] = vzero;
        bf16x8 gf[2];
        #pragma unroll
        for (int mt = 0; mt < 2; ++mt)
            gf[mt] = *(const bf16x8*)(sy + ybyte(hb + mt * 16 + lr, lk * 16));
        #pragma unroll
        for (int mt = 0; mt < 2; ++mt)
            #pragma unroll
            for (int ct = 0; ct < 2; ++ct)
                acc[mt][ct] = __builtin_amdgcn_mfma_f32_16x16x32_bf16(gf[mt], Af[ct], acc[mt][ct], 0, 0, 0);
        __syncthreads();
        #pragma unroll
        for (int mt = 0; mt < 2; ++mt)
            #pragma unroll
            for (int ct = 0; ct < 2; ++ct) {
                const int cp = ct * 16 + lr;
                uint2 hv;
                hv.x = cvt_pk_bf16(acc[mt][ct][0], acc[mt][ct][1]);
                hv.y = cvt_pk_bf16(acc[mt][ct][2], acc[mt][ct][3]);
                *(uint2*)&sh3[cp * 136 + hb + mt * 16 + lk * 4] = hv;
            }
    }
    __syncthreads();

    {
        f32x4 acc[2][2];
        #pragma unroll
        for (int mt = 0; mt < 2; ++mt) {
            const ushort4 bu = *(const ushort4*)(b1g + hb + mt * 16 + lk * 4);
            f32x4 bvv = {bf2f(bu.x), bf2f(bu.y), bf2f(bu.z), bf2f(bu.w)};
            acc[mt][0] = bvv;
            acc[mt][1] = bvv;
        }
        #pragma unroll
        for (int ks = 0; ks < 4; ++ks) {
            bf16x8 wf[2], hf[2];
            #pragma unroll
            for (int mt = 0; mt < 2; ++mt)
                wf[mt] = *(const bf16x8*)(W1g + ((size_t)(hb + mt * 16 + lr)) * HH + ks * 32 + lk * 8);
            #pragma unroll
            for (int ct = 0; ct < 2; ++ct)
                hf[ct] = *(const bf16x8*)(sh3 + (ct * 16 + lr) * 136 + ks * 32 + lk * 8);
            #pragma unroll
            for (int mt = 0; mt < 2; ++mt)
                #pragma unroll
                for (int ct = 0; ct < 2; ++ct)
                    acc[mt][ct] = __builtin_amdgcn_mfma_f32_16x16x32_bf16(wf[mt], hf[ct], acc[mt][ct], 0, 0, 0);
        }
        float s[2][4];
        #pragma unroll
        for (int mt = 0; mt < 2; ++mt)
            #pragma unroll
            for (int r = 0; r < 4; ++r) {
                float v = fmaxf(acc[mt][0][r], 0.f);
                if (lr < CC - 16) v += fmaxf(acc[mt][1][r], 0.f);
                s[mt][r] = v;
            }
        #pragma unroll
        for (int m = 1; m < 16; m <<= 1)
            #pragma unroll
            for (int mt = 0; mt < 2; ++mt)
                #pragma unroll
                for (int r = 0; r < 4; ++r)
                    s[mt][r] += __shfl_xor(s[mt][r], m);
        if (lr == 0) {
            const float inv = 1.0f / 22.0f;
            #pragma unroll
            for (int mt = 0; mt < 2; ++mt) {
                uint2 st;
                st.x = cvt_pk_bf16(s[mt][0] * inv, s[mt][1] * inv);
                st.y = cvt_pk_bf16(s[mt][2] * inv, s[mt][3] * inv);
                *(uint2*)(outg + (size_t)bt * HH + hb + mt * 16 + lk * 4) = st;
            }
        }
    }
}

__global__ __launch_bounds__(256, 4) void tgcn_kernel(
    const void* __restrict__ x, const void* __restrict__ A,
    const void* __restrict__ W0, const void* __restrict__ b0,
    const void* __restrict__ W1, const void* __restrict__ b1,
    void* __restrict__ out, const unsigned short* __restrict__ wsW,
    int use_split)
{
    __shared__ __align__(16) char smem[39104];   // 4 blocks/CU

    const int tid = threadIdx.x;
    const int blk = blockIdx.x;
    const int isbf = inputs_are_bf16((const unsigned short*)A, tid);

    if (isbf) {
        for (int it = 0; it < NITER; ++it) {
            run_block_bf16((const unsigned short*)x, (const unsigned short*)A,
                           (const unsigned short*)W0, (const unsigned short*)b0,
                           (const unsigned short*)W1, (const unsigned short*)b1,
                           (unsigned short*)out, it * NBLK + blk, tid, smem);
            __syncthreads();
        }
    } else if (use_split) {
        run_split_loop((const float*)x, (const float*)A,
                       (const float*)b0, (const float*)b1,
                       wsW, (float*)out, blk, tid, smem);
    } else {
        float* sA  = (float*)smem;                 // 1936B (later sRed)
        float* sX  = (float*)(smem + 1936);        // 16896B (later h2)
        float* sH1 = (float*)(smem + 18832);       // 16896B (later h3)
        for (int it = 0; it < NITER; ++it) {
            run_block_f32((const float*)x, (const float*)A,
                          (const float*)W0, (const float*)b0,
                          (const float*)W1, (const float*)b1,
                          (float*)out, it * NBLK + blk, tid, sA, sX, sH1);
            __syncthreads();
        }
    }
}

extern "C" void kernel_launch(void* const* d_in, const int* in_sizes, int n_in,
                              void* d_out, int out_size, void* d_ws, size_t ws_size,
                              hipStream_t stream) {
    unsigned short* wsW = (unsigned short*)d_ws;
    const int use_split = (ws_size >= (size_t)(81920 * 2)) ? 1 : 0;

    if (use_split)
        convert_weights<<<160, 256, 0, stream>>>(
            (const float*)d_in[2], (const float*)d_in[4],
            (const unsigned short*)d_in[1], wsW);
    tgcn_kernel<<<NBLK, 256, 0, stream>>>(
        d_in[0], d_in[1], d_in[2], d_in[3], d_in[4], d_in[5], d_out,
        wsW, use_split);
}